// Round 1
// 656.363 us; speedup vs baseline: 1.0669x; 1.0669x over previous
//
#include <hip/hip_runtime.h>
#include <cstdint>
#include <cstddef>

#define BB 2
#define SS 2048
#define EE 1024
#define HH 16
#define DH 64
#define KKSEL 409   // kk = int(2048*0.2)
#define QT 16       // query rows per attention block
#define PST 136     // probs LDS row stride (bf16 elems) per half (128 cols + pad)

typedef __attribute__((ext_vector_type(8))) short bf16x8;
typedef __attribute__((ext_vector_type(4))) float f32x4;
typedef unsigned short ushort_t;

__device__ __forceinline__ unsigned short f2bf(float f){
    unsigned u = __float_as_uint(f);
    u += 0x7fffu + ((u >> 16) & 1u);          // RNE
    return (unsigned short)(u >> 16);
}
__device__ __forceinline__ float bf2f(unsigned short h){
    return __uint_as_float(((unsigned)h) << 16);
}
__device__ __forceinline__ unsigned sortkey(float f){
    unsigned u = __float_as_uint(f);
    return (u & 0x80000000u) ? ~u : (u | 0x80000000u);
}
__device__ __forceinline__ float inv_sortkey(unsigned k){
    unsigned u = (k & 0x80000000u) ? (k & 0x7fffffffu) : ~k;
    return __uint_as_float(u);
}
__device__ __forceinline__ void split8(const float* f, bf16x8& h, bf16x8& l){
    #pragma unroll
    for (int j = 0; j < 8; ++j){
        ushort_t hh = f2bf(f[j]);
        h[j] = (short)hh;
        l[j] = (short)f2bf(f[j] - bf2f(hh));
    }
}

// ---------------------------------------------------------------------------
// convert_wt4: 4x fused. W (1024x1024 [k][n]) -> W^T bf16 hi/lo ([n][k])
// ---------------------------------------------------------------------------
struct CvtArgs {
    const float* W[4];
    ushort_t* H[4];
    ushort_t* L[4];
};

__global__ __launch_bounds__(256) void convert_wt4(CvtArgs a)
{
    __shared__ float T[64][65];
    const int z = blockIdx.z;
    const float* __restrict__ W = a.W[z];
    ushort_t* __restrict__ Ht = a.H[z];
    ushort_t* __restrict__ Lt = a.L[z];

    const int tid = threadIdx.x;
    const int ty = tid >> 4, tx = tid & 15;
    const int n0 = blockIdx.x * 64, k0 = blockIdx.y * 64;
    #pragma unroll
    for (int i = 0; i < 4; ++i){
        const int kl = ty + i * 16;
        float4 w = *(const float4*)&W[(size_t)(k0 + kl) * EE + n0 + tx * 4];
        T[kl][tx*4 + 0] = w.x; T[kl][tx*4 + 1] = w.y;
        T[kl][tx*4 + 2] = w.z; T[kl][tx*4 + 3] = w.w;
    }
    __syncthreads();
    #pragma unroll
    for (int i = 0; i < 4; ++i){
        const int nl = ty + i * 16;
        ushort4 h, l;
        ushort_t* hp = &h.x; ushort_t* lp = &l.x;
        #pragma unroll
        for (int j = 0; j < 4; ++j){
            const float v = T[tx*4 + j][nl];
            ushort_t hh = f2bf(v);
            hp[j] = hh;
            lp[j] = f2bf(v - bf2f(hh));
        }
        const size_t o = (size_t)(n0 + nl) * EE + k0 + tx * 4;
        *(ushort4*)&Ht[o] = h;
        *(ushort4*)&Lt[o] = l;
    }
}

// ---------------------------------------------------------------------------
// Split-bf16 MFMA GEMM body (see previous round). buf = 2 stages x 32 KB.
// MODE 0: Q -> bf16 hi/lo [bh][s][d]   MODE 1: K -> hi, scaled by ts[h]
// MODE 2: V -> hi, transposed [bh][d][s]   MODE 3: fp32 row-major
// ---------------------------------------------------------------------------
template<int MODE>
__device__ __forceinline__ void gemm_body(
        const float* __restrict__ X,
        const ushort_t* __restrict__ Wth, const ushort_t* __restrict__ Wtl,
        const float* __restrict__ bias, const float* __restrict__ ts,
        float* __restrict__ OutF, ushort_t* __restrict__ OutH,
        ushort_t* __restrict__ OutL, ushort_t* buf)
{
    const int tid  = threadIdx.x;
    const int lane = tid & 63, wave = tid >> 6;
    const int c16  = lane & 15, qd = lane >> 4;
    const int m0 = blockIdx.y * 128, n0 = blockIdx.x * 128;
    const int wm = (wave >> 1) * 64, wn = (wave & 1) * 64;
    const int lrow = tid >> 1, lkg = (tid & 1) * 16;

    f32x4 acc[4][4];
    #pragma unroll
    for (int a = 0; a < 4; ++a)
        #pragma unroll
        for (int b = 0; b < 4; ++b) acc[a][b] = (f32x4){0.f,0.f,0.f,0.f};

    const float* Xr = X + (size_t)(m0 + lrow) * EE + lkg;
    const ushort_t* Whr = Wth + (size_t)(n0 + lrow) * EE + lkg;
    const ushort_t* Wlr = Wtl + (size_t)(n0 + lrow) * EE + lkg;

    // prologue: stage k0 = 0 into stage 0
    {
        float fx[16];
        *(float4*)&fx[0]  = *(const float4*)&Xr[0];
        *(float4*)&fx[4]  = *(const float4*)&Xr[4];
        *(float4*)&fx[8]  = *(const float4*)&Xr[8];
        *(float4*)&fx[12] = *(const float4*)&Xr[12];
        bf16x8 w0 = *(const bf16x8*)&Whr[0];
        bf16x8 w1 = *(const bf16x8*)&Whr[8];
        bf16x8 w2 = *(const bf16x8*)&Wlr[0];
        bf16x8 w3 = *(const bf16x8*)&Wlr[8];
        bf16x8 h0, l0, h1, l1;
        split8(fx, h0, l0); split8(fx + 8, h1, l1);
        ushort_t* S = buf;
        *(bf16x8*)&S[lrow*32 + lkg]           = h0;
        *(bf16x8*)&S[lrow*32 + lkg + 8]       = h1;
        *(bf16x8*)&S[4096 + lrow*32 + lkg]    = l0;
        *(bf16x8*)&S[4096 + lrow*32 + lkg+8]  = l1;
        *(bf16x8*)&S[8192 + lrow*32 + lkg]    = w0;
        *(bf16x8*)&S[8192 + lrow*32 + lkg+8]  = w1;
        *(bf16x8*)&S[12288 + lrow*32 + lkg]   = w2;
        *(bf16x8*)&S[12288 + lrow*32 + lkg+8] = w3;
    }
    __syncthreads();

    int cur = 0;
    for (int k0 = 0; k0 < EE; k0 += 32){
        const bool more = (k0 + 32) < EE;
        float fx[16];
        bf16x8 gw[4];
        if (more){
            const float* xp = Xr + k0 + 32;
            *(float4*)&fx[0]  = *(const float4*)&xp[0];
            *(float4*)&fx[4]  = *(const float4*)&xp[4];
            *(float4*)&fx[8]  = *(const float4*)&xp[8];
            *(float4*)&fx[12] = *(const float4*)&xp[12];
            gw[0] = *(const bf16x8*)&Whr[k0 + 32];
            gw[1] = *(const bf16x8*)&Whr[k0 + 40];
            gw[2] = *(const bf16x8*)&Wlr[k0 + 32];
            gw[3] = *(const bf16x8*)&Wlr[k0 + 40];
        }
        const ushort_t* S  = buf + cur * 16384;
        const ushort_t* A0 = S;
        const ushort_t* A1 = S + 4096;
        const ushort_t* B0 = S + 8192;
        const ushort_t* B1 = S + 12288;
        bf16x8 afh[4], afl[4], bfh[4], bfl[4];
        #pragma unroll
        for (int i = 0; i < 4; ++i){
            afh[i] = *(const bf16x8*)&A0[(wm + i*16 + c16)*32 + qd*8];
            afl[i] = *(const bf16x8*)&A1[(wm + i*16 + c16)*32 + qd*8];
            bfh[i] = *(const bf16x8*)&B0[(wn + i*16 + c16)*32 + qd*8];
            bfl[i] = *(const bf16x8*)&B1[(wn + i*16 + c16)*32 + qd*8];
        }
        #pragma unroll
        for (int a = 0; a < 4; ++a){
            #pragma unroll
            for (int b = 0; b < 4; ++b){
                if (MODE == 2){   // X first: D rows <- s
                    acc[a][b] = __builtin_amdgcn_mfma_f32_16x16x32_bf16(afh[a], bfh[b], acc[a][b], 0,0,0);
                    acc[a][b] = __builtin_amdgcn_mfma_f32_16x16x32_bf16(afh[a], bfl[b], acc[a][b], 0,0,0);
                    acc[a][b] = __builtin_amdgcn_mfma_f32_16x16x32_bf16(afl[a], bfh[b], acc[a][b], 0,0,0);
                } else {          // W first: D rows <- n
                    acc[a][b] = __builtin_amdgcn_mfma_f32_16x16x32_bf16(bfh[a], afh[b], acc[a][b], 0,0,0);
                    acc[a][b] = __builtin_amdgcn_mfma_f32_16x16x32_bf16(bfh[a], afl[b], acc[a][b], 0,0,0);
                    acc[a][b] = __builtin_amdgcn_mfma_f32_16x16x32_bf16(bfl[a], afh[b], acc[a][b], 0,0,0);
                }
            }
        }
        if (more){
            bf16x8 h0, l0, h1, l1;
            split8(fx, h0, l0); split8(fx + 8, h1, l1);
            ushort_t* N = buf + (cur ^ 1) * 16384;
            *(bf16x8*)&N[lrow*32 + lkg]           = h0;
            *(bf16x8*)&N[lrow*32 + lkg + 8]       = h1;
            *(bf16x8*)&N[4096 + lrow*32 + lkg]    = l0;
            *(bf16x8*)&N[4096 + lrow*32 + lkg+8]  = l1;
            *(bf16x8*)&N[8192 + lrow*32 + lkg]    = gw[0];
            *(bf16x8*)&N[8192 + lrow*32 + lkg+8]  = gw[1];
            *(bf16x8*)&N[12288 + lrow*32 + lkg]   = gw[2];
            *(bf16x8*)&N[12288 + lrow*32 + lkg+8] = gw[3];
            __syncthreads();
            cur ^= 1;
        }
    }

    if (MODE == 3){
        #pragma unroll
        for (int a = 0; a < 4; ++a){
            const int ng = n0 + wn + a*16 + qd*4;
            float4 b4 = *(const float4*)&bias[ng];
            const float bb[4] = {b4.x, b4.y, b4.z, b4.w};
            #pragma unroll
            for (int b = 0; b < 4; ++b){
                const int mg = m0 + wm + b*16 + c16;
                float4 o;
                o.x = acc[a][b][0] + bb[0]; o.y = acc[a][b][1] + bb[1];
                o.z = acc[a][b][2] + bb[2]; o.w = acc[a][b][3] + bb[3];
                *(float4*)&OutF[(size_t)mg * EE + ng] = o;
            }
        }
    } else if (MODE == 0){
        #pragma unroll
        for (int a = 0; a < 4; ++a){
            const int ng = n0 + wn + a*16 + qd*4;
            const int h = ng >> 6, d0 = ng & 63;
            float4 b4 = *(const float4*)&bias[ng];
            const float bb[4] = {b4.x, b4.y, b4.z, b4.w};
            #pragma unroll
            for (int b = 0; b < 4; ++b){
                const int mg = m0 + wm + b*16 + c16;
                const int bi = mg >> 11, s = mg & (SS - 1);
                ushort4 hv, lv;
                ushort_t* hp = &hv.x; ushort_t* lp = &lv.x;
                #pragma unroll
                for (int r = 0; r < 4; ++r){
                    const float v = acc[a][b][r] + bb[r];
                    ushort_t hh = f2bf(v);
                    hp[r] = hh;
                    lp[r] = f2bf(v - bf2f(hh));
                }
                const size_t o = (((size_t)(bi * HH + h)) * SS + s) * DH + d0;
                *(ushort4*)&OutH[o] = hv;
                *(ushort4*)&OutL[o] = lv;
            }
        }
    } else if (MODE == 1){
        #pragma unroll
        for (int a = 0; a < 4; ++a){
            const int ng = n0 + wn + a*16 + qd*4;
            const int h = ng >> 6, d0 = ng & 63;
            const float tsc = ts[h];
            float4 b4 = *(const float4*)&bias[ng];
            const float bb[4] = {b4.x, b4.y, b4.z, b4.w};
            #pragma unroll
            for (int b = 0; b < 4; ++b){
                const int mg = m0 + wm + b*16 + c16;
                const int bi = mg >> 11, s = mg & (SS - 1);
                ushort4 hv;
                ushort_t* hp = &hv.x;
                #pragma unroll
                for (int r = 0; r < 4; ++r)
                    hp[r] = f2bf((acc[a][b][r] + bb[r]) * tsc);
                *(ushort4*)&OutH[(((size_t)(bi * HH + h)) * SS + s) * DH + d0] = hv;
            }
        }
    } else { // MODE 2: V^T hi only
        #pragma unroll
        for (int a = 0; a < 4; ++a){
            const int mg = m0 + wm + a*16 + qd*4;
            const int bi = mg >> 11, s0 = mg & (SS - 1);
            #pragma unroll
            for (int b = 0; b < 4; ++b){
                const int ng = n0 + wn + b*16 + c16;
                const int h = ng >> 6, d = ng & 63;
                const float bv = bias[ng];
                ushort4 hv;
                ushort_t* hp = &hv.x;
                #pragma unroll
                for (int r = 0; r < 4; ++r) hp[r] = f2bf(acc[a][b][r] + bv);
                *(ushort4*)&OutH[(((size_t)(bi * HH + h)) * DH + d) * SS + s0] = hv;
            }
        }
    }
}

// Fused Q/K/V projections: blockIdx.z picks the problem. 768 blocks keep
// 2+ blocks/CU resident instead of the 256-block (1 wave/SIMD) launches.
__global__ __launch_bounds__(256) void gemm_qkv(
        const float* __restrict__ q, const float* __restrict__ k,
        const float* __restrict__ v,
        const ushort_t* __restrict__ Wqh, const ushort_t* __restrict__ Wql,
        const ushort_t* __restrict__ Wkh, const ushort_t* __restrict__ Wkl,
        const ushort_t* __restrict__ Wvh, const ushort_t* __restrict__ Wvl,
        const float* __restrict__ bq, const float* __restrict__ bk,
        const float* __restrict__ bv, const float* __restrict__ ts,
        ushort_t* __restrict__ Qh, ushort_t* __restrict__ Ql,
        ushort_t* __restrict__ Kh, ushort_t* __restrict__ Vth)
{
    __shared__ ushort_t buf[2 * 16384];
    const int z = blockIdx.z;
    if (z == 0)
        gemm_body<0>(q, Wqh, Wql, bq, nullptr, nullptr, Qh, Ql, buf);
    else if (z == 1)
        gemm_body<1>(k, Wkh, Wkl, bk, ts, nullptr, Kh, nullptr, buf);
    else
        gemm_body<2>(v, Wvh, Wvl, bv, nullptr, nullptr, Vth, nullptr, buf);
}

__global__ __launch_bounds__(256) void gemm_out(
        const float* __restrict__ X,
        const ushort_t* __restrict__ Wth, const ushort_t* __restrict__ Wtl,
        const float* __restrict__ bias, float* __restrict__ OutF)
{
    __shared__ ushort_t buf[2 * 16384];
    gemm_body<3>(X, Wth, Wtl, bias, nullptr, OutF, nullptr, nullptr, buf);
}

// ---------------------------------------------------------------------------
// Fused attention, 512 threads / 8 waves; wave owns 256 score columns.
// Top-k threshold: LDS exchange (plain float scores) so each wave owns full
// rows; integer-key bisection with bounds from the row min/max; per-candidate
// count via __ballot -> independent SGPR-pair v_cmp chains (no vcc serial
// hazard). Early exit when count == kk (exact: any separating mid reproduces
// the reference's >= min_topk set; ties converge to the exact key).
// ---------------------------------------------------------------------------
__global__ __launch_bounds__(512, 4) void attn_kernel(
        const ushort_t* __restrict__ Qh, const ushort_t* __restrict__ Ql,
        const ushort_t* __restrict__ Khi, const ushort_t* __restrict__ Vth,
        float* __restrict__ AO)
{
    __shared__ __align__(16) char uni[65536];
    __shared__ float wsums[8][16];
    __shared__ float thr16[16];

    const int tid  = threadIdx.x;
    const int lane = tid & 63;
    const int wave = tid >> 6;
    const int qd   = lane >> 4;
    const int c16  = lane & 15;
    const unsigned Bx = blockIdx.x;
    const int xcd  = Bx & 7;
    const int qq   = Bx >> 3;
    const int tile = qq & 127;
    const int bh   = (qq >> 7) * 8 + xcd;
    const int t0   = tile * QT;
    const int wbase = wave * 256;

    // ---- Q fragments (pre-split hi/lo) ----
    bf16x8 qh[2], ql[2];
    {
        const size_t qbase = ((size_t)bh * SS + t0 + c16) * DH;
        #pragma unroll
        for (int kc = 0; kc < 2; ++kc){
            qh[kc] = *(const bf16x8*)&Qh[qbase + kc*32 + qd*8];
            ql[kc] = *(const bf16x8*)&Ql[qbase + kc*32 + qd*8];
        }
    }

    // ---- phase 1: scores (K hi-only, Q split) ----
    f32x4 acc[16];
    const ushort_t* Kh = Khi + (size_t)bh * SS * DH;
    #pragma unroll
    for (int t = 0; t < 16; ++t){
        f32x4 a = {0.f, 0.f, 0.f, 0.f};
        const int srow = wbase + t*16 + c16;
        const ushort_t* kp = Kh + (size_t)srow * DH + qd*8;
        #pragma unroll
        for (int kc = 0; kc < 2; ++kc){
            bf16x8 kh = *(const bf16x8*)(kp + kc*32);
            a = __builtin_amdgcn_mfma_f32_16x16x32_bf16(qh[kc], kh, a, 0, 0, 0);
            a = __builtin_amdgcn_mfma_f32_16x16x32_bf16(ql[kc], kh, a, 0, 0, 0);
        }
        acc[t] = a;
    }

    // ---- scale + diag boost (plain float scores kept in acc) ----
    #pragma unroll
    for (int t = 0; t < 16; ++t){
        const int colg = wbase + t*16 + c16;
        #pragma unroll
        for (int r = 0; r < 4; ++r){
            float v = acc[t][r] * 0.15625f;        // 1/8 * 1.25
            if (colg == t0 + qd*4 + r) v *= 1.15f;
            acc[t][r] = v;
        }
    }

    // ---- phase 2: exact top-k threshold (exchange + key bisection) ----
    float* ex = (float*)uni;   // 8 rows x 2048 fp32
    #pragma unroll
    for (int half = 0; half < 2; ++half){
        if ((qd >> 1) == half){
            const int rl = (qd & 1) * 4;
            #pragma unroll
            for (int t = 0; t < 16; ++t)
                #pragma unroll
                for (int r = 0; r < 4; ++r)
                    ex[(rl + r) * SS + wbase + t*16 + c16] = acc[t][r];
        }
        __syncthreads();
        float cand[32];
        #pragma unroll
        for (int j = 0; j < 32; ++j)
            cand[j] = ex[wave * SS + lane + 64*j];
        // tight bisection bounds from the row's min/max
        float mx = cand[0], mn = cand[0];
        #pragma unroll
        for (int j = 1; j < 32; ++j){
            mx = fmaxf(mx, cand[j]);
            mn = fminf(mn, cand[j]);
        }
        #pragma unroll
        for (int off = 1; off < 64; off <<= 1){
            mx = fmaxf(mx, __shfl_xor(mx, off, 64));
            mn = fminf(mn, __shfl_xor(mn, off, 64));
        }
        unsigned lo = sortkey(mn), hi = sortkey(mx) + 1u;
        #pragma unroll 1
        for (int it = 0; it < 32 && (hi - lo) > 1u; ++it){
            const unsigned mid = lo + ((hi - lo) >> 1);
            const float midf = inv_sortkey(mid);
            int c = 0;
            #pragma unroll
            for (int j = 0; j < 32; ++j)
                c += (int)__popcll(__ballot(cand[j] >= midf));
            if (c == KKSEL){ lo = mid; break; }
            if (c > KKSEL) lo = mid; else hi = mid;
        }
        if (lane == 0) thr16[half*8 + wave] = inv_sortkey(lo);
        __syncthreads();
    }

    // ---- phase 3: boost + exp + row sums (float compare == reference) ----
    float thr[4];
    #pragma unroll
    for (int r = 0; r < 4; ++r) thr[r] = thr16[qd*4 + r];
    float psum[4] = {0.f, 0.f, 0.f, 0.f};
    #pragma unroll
    for (int t = 0; t < 16; ++t){
        #pragma unroll
        for (int r = 0; r < 4; ++r){
            float s = acc[t][r];
            s *= (s >= thr[r]) ? 1.15f : 1.0f;
            const float e = __expf(s);
            acc[t][r] = e;
            psum[r] += e;
        }
    }
    #pragma unroll
    for (int off = 1; off <= 8; off <<= 1){
        #pragma unroll
        for (int r = 0; r < 4; ++r) psum[r] += __shfl_xor(psum[r], off, 64);
    }
    if (c16 == 0){
        #pragma unroll
        for (int r = 0; r < 4; ++r) wsums[wave][qd*4 + r] = psum[r];
    }
    __syncthreads();
    float pinv[4];
    #pragma unroll
    for (int r = 0; r < 4; ++r){
        const int row = qd*4 + r;
        float s = 0.f;
        #pragma unroll
        for (int w = 0; w < 8; ++w) s += wsums[w][row];
        pinv[r] = 1.f / s;
    }

    // ---- phase 4: O = P @ V (two 128-col halves per wave) ----
    const ushort_t* Vh = Vth + (size_t)bh * DH * SS;
    ushort_t* pw = (ushort_t*)uni + wave * (QT * PST);   // per-wave region
    f32x4 oacc[4];
    #pragma unroll
    for (int dt = 0; dt < 4; ++dt) oacc[dt] = (f32x4){0.f, 0.f, 0.f, 0.f};

    #pragma unroll
    for (int half = 0; half < 2; ++half){
        #pragma unroll
        for (int tt = 0; tt < 8; ++tt){
            const int t = half*8 + tt;
            #pragma unroll
            for (int r = 0; r < 4; ++r)
                pw[(qd*4 + r) * PST + tt*16 + c16] = f2bf(acc[t][r] * pinv[r]);
        }
        // per-wave region: same-wave ds_write -> ds_read, no barrier needed
        #pragma unroll
        for (int kc = 0; kc < 4; ++kc){
            bf16x8 pf = *(const bf16x8*)&pw[c16 * PST + kc*32 + qd*8];
            const int sbase = wbase + half*128 + kc*32 + qd*8;
            #pragma unroll
            for (int dt = 0; dt < 4; ++dt){
                const int d = dt*16 + c16;
                bf16x8 vh = *(const bf16x8*)(Vh + (size_t)d * SS + sbase);
                oacc[dt] = __builtin_amdgcn_mfma_f32_16x16x32_bf16(pf, vh, oacc[dt], 0, 0, 0);
            }
        }
    }

    // ---- cross-wave O reduction + fp32 store ----
    __syncthreads();   // all probs reads done before red overwrites the union
    float* red = (float*)uni;   // 8 x 16 x 65
    #pragma unroll
    for (int dt = 0; dt < 4; ++dt)
        #pragma unroll
        for (int r = 0; r < 4; ++r)
            red[(wave*16 + qd*4 + r) * 65 + dt*16 + c16] = oacc[dt][r];
    __syncthreads();

    const int b = bh >> 4, h = bh & 15;
    {
        const int r  = tid >> 5;           // 0..15
        const int c2 = (tid & 31) * 2;     // 0,2,..,62
        float s0 = 0.f, s1 = 0.f;
        #pragma unroll
        for (int w = 0; w < 8; ++w){
            s0 += red[(w*16 + r) * 65 + c2];
            s1 += red[(w*16 + r) * 65 + c2 + 1];
        }
        float2 o; o.x = s0; o.y = s1;
        *(float2*)&AO[((size_t)b * SS + t0 + r) * EE + h*DH + c2] = o;
    }
}

// ---------------------------------------------------------------------------
extern "C" void kernel_launch(void* const* d_in, const int* in_sizes, int n_in,
                              void* d_out, int out_size, void* d_ws, size_t ws_size,
                              hipStream_t stream)
{
    const float* query = (const float*)d_in[0];
    const float* key   = (const float*)d_in[1];
    const float* value = (const float*)d_in[2];
    const float* Wq    = (const float*)d_in[3];
    const float* bq    = (const float*)d_in[4];
    const float* Wk    = (const float*)d_in[5];
    const float* bk    = (const float*)d_in[6];
    const float* Wv    = (const float*)d_in[7];
    const float* bv    = (const float*)d_in[8];
    const float* Wo    = (const float*)d_in[9];
    const float* bo    = (const float*)d_in[10];
    const float* ts    = (const float*)d_in[11];
    float* out = (float*)d_out;
    char* w = (char*)d_ws;

    const size_t MB = 1u << 20;
    ushort_t* Qh  = (ushort_t*)(w + 0 * MB);
    ushort_t* Ql  = (ushort_t*)(w + 8 * MB);
    ushort_t* Kh  = (ushort_t*)(w + 16 * MB);
    ushort_t* Vth = (ushort_t*)(w + 24 * MB);
    float*    AOw = (float*)   (w + 32 * MB);   // 16 MB fp32 (written by attn)
    // QKV converted weights live inside the AOw region: they are fully
    // consumed by gemm_qkv before attn writes AOw (stream-ordered).
    ushort_t* Wqh = (ushort_t*)(w + 32 * MB);
    ushort_t* Wql = (ushort_t*)(w + 34 * MB);
    ushort_t* Wkh = (ushort_t*)(w + 36 * MB);
    ushort_t* Wkl = (ushort_t*)(w + 38 * MB);
    ushort_t* Wvh = (ushort_t*)(w + 40 * MB);
    ushort_t* Wvl = (ushort_t*)(w + 42 * MB);
    ushort_t* Woh = (ushort_t*)(w + 48 * MB);
    ushort_t* Wol = (ushort_t*)(w + 50 * MB);

    CvtArgs ca;
    ca.W[0] = Wq;  ca.W[1] = Wk;  ca.W[2] = Wv;  ca.W[3] = Wo;
    ca.H[0] = Wqh; ca.H[1] = Wkh; ca.H[2] = Wvh; ca.H[3] = Woh;
    ca.L[0] = Wql; ca.L[1] = Wkl; ca.L[2] = Wvl; ca.L[3] = Wol;

    // all 4 weight conversions in one launch
    hipLaunchKernelGGL(convert_wt4, dim3(16, 16, 4), dim3(256), 0, stream, ca);
    // Q, K, V projections fused into one launch (768 blocks)
    hipLaunchKernelGGL(gemm_qkv, dim3(8, 32, 3), dim3(256), 0, stream,
                       query, key, value, Wqh, Wql, Wkh, Wkl, Wvh, Wvl,
                       bq, bk, bv, ts, Qh, Ql, Kh, Vth);
    // attention -> AO fp32
    hipLaunchKernelGGL(attn_kernel, dim3(BB * HH * (SS / QT)), dim3(512), 0, stream,
                       Qh, Ql, Kh, Vth, AOw);
    // output projection
    hipLaunchKernelGGL(gemm_out, dim3(8, 32), dim3(256), 0, stream,
                       AOw, Woh, Wol, bo, out);
}